// Round 5
// baseline (1860.564 us; speedup 1.0000x reference)
//
#include <hip/hip_runtime.h>
#include <cstdint>
#include <cstddef>

// Problem constants
#define N_ 4096
#define B_ 2
#define V_ 4
#define D_ 256
#define C_ 3
#define H_ 512

#define PLANE 1048576   // N_*D_ elements per split plane
#define WPLANE 131072   // H_*D_ elements per W1T split plane
#define NEG_INF (-__builtin_inff())

typedef __attribute__((ext_vector_type(8))) short bf16x8;   // 8 bf16 in 4 VGPRs
typedef __attribute__((ext_vector_type(4))) float f32x4;

// ---------------------------------------------------------------------------
__device__ __forceinline__ void gload16(const void* g, void* l) {
    __builtin_amdgcn_global_load_lds(
        (const __attribute__((address_space(1))) void*)g,
        (__attribute__((address_space(3))) void*)l,
        16, 0, 0);
}

// RNE float->bf16
__device__ __forceinline__ unsigned short f2bf(float x) {
    unsigned u = __builtin_bit_cast(unsigned, x);
    u += 0x7FFFu + ((u >> 16) & 1u);
    return (unsigned short)(u >> 16);
}
__device__ __forceinline__ float bf2f(unsigned short h) {
    unsigned u = ((unsigned)h) << 16;
    return __builtin_bit_cast(float, u);
}
__device__ __forceinline__ void split3(float x, unsigned short& h, unsigned short& m,
                                       unsigned short& l) {
    h = f2bf(x);
    float r = x - bf2f(h);
    m = f2bf(r);
    l = f2bf(r - bf2f(m));
}

// Online-softmax + argmax state merge. st = {M, S, w0, w1, w2, av, ai, pad}
__device__ __forceinline__ void merge_state(float* st, float M2, float S2,
                                            float w0, float w1, float w2,
                                            float av2, float ai2) {
    float M1 = st[0];
    if (M2 > M1) {
        float e = __expf(M1 - M2);     // M1=-inf -> e=0, clean
        st[0] = M2;
        st[1] = fmaf(st[1], e, S2);
        st[2] = fmaf(st[2], e, w0);
        st[3] = fmaf(st[3], e, w1);
        st[4] = fmaf(st[4], e, w2);
    } else {
        float e = __expf(M2 - M1);
        st[1] = fmaf(S2, e, st[1]);
        st[2] = fmaf(w0, e, st[2]);
        st[3] = fmaf(w1, e, st[3]);
        st[4] = fmaf(w2, e, st[4]);
    }
    if (av2 > st[5] || (av2 == st[5] && ai2 < st[6])) { st[5] = av2; st[6] = ai2; }
}

// ---------------------------------------------------------------------------
__global__ __launch_bounds__(64) void zero_accum_kernel(float* loss_sum, int* hm) {
    int t = threadIdx.x;
    if (t < 24) loss_sum[t] = 0.0f;
    if (t < 12) hm[t] = 0;
}

// ---------------------------------------------------------------------------
// Split desc fp32 -> 3 bf16 planes per (b,v):  SP[(bv*3+l)][n][d]
__global__ __launch_bounds__(256) void split_kernel(const float* __restrict__ desc,
                                                    unsigned short* __restrict__ SP) {
    int t = blockIdx.x * 256 + threadIdx.x;
    int d4 = t & 63;
    int v  = (t >> 6) & 3;
    int n  = (t >> 8) & 4095;
    int b  = t >> 20;
    const float4 x = *(const float4*)(desc + (((size_t)(b * N_ + n) * V_ + v) << 8) + d4 * 4);
    ushort4 hv, mv, lv;
    split3(x.x, hv.x, mv.x, lv.x);
    split3(x.y, hv.y, mv.y, lv.y);
    split3(x.z, hv.z, mv.z, lv.z);
    split3(x.w, hv.w, mv.w, lv.w);
    size_t base = (size_t)((b * V_ + v) * 3) * PLANE + n * D_ + d4 * 4;
    *(ushort4*)(SP + base)              = hv;
    *(ushort4*)(SP + base + PLANE)      = mv;
    *(ushort4*)(SP + base + 2 * PLANE)  = lv;
}

// W1 [D][H] -> transposed split planes W1T[l][h][k]
__global__ __launch_bounds__(256) void w1split_kernel(const float* __restrict__ W1,
                                                      unsigned short* __restrict__ W1T) {
    int t = blockIdx.x * 256 + threadIdx.x;
    int h = t & 511;
    int k = t >> 9;
    float x = W1[(size_t)k * H_ + h];
    unsigned short hv, mv, lv;
    split3(x, hv, mv, lv);
    size_t o = (size_t)h * D_ + k;
    W1T[o] = hv; W1T[o + WPLANE] = mv; W1T[o + 2 * WPLANE] = lv;
}

// ---------------------------------------------------------------------------
__global__ __launch_bounds__(256) void norms_kernel(const float* __restrict__ desc,
                                                    float* __restrict__ invn) {
    int gw   = (blockIdx.x * 256 + threadIdx.x) >> 6;
    int lane = threadIdx.x & 63;
    int bv = gw >> 12;
    int n  = gw & (N_ - 1);
    int b  = bv >> 2, v = bv & 3;
    const float* p = desc + ((size_t)(b * N_ + n) * V_ + v) * D_;
    float4 x = *(const float4*)(p + lane * 4);
    float s = x.x * x.x + x.y * x.y + x.z * x.z + x.w * x.w;
    #pragma unroll
    for (int off = 32; off >= 1; off >>= 1) s += __shfl_xor(s, off, 64);
    if (lane == 0) invn[gw] = 1.0f / fmaxf(sqrtf(s), 1e-12f);
}

// ---------------------------------------------------------------------------
// FUSED gram + row/col online-softmax/argmax reductions (never materializes S).
// Block = 128-row strip x 256-col chunk, two 128x128 tiles.  6-pass bf16-split
// emulated-fp32 MFMA (exact to ~2^-24).  Emits per-block partial states:
//   RP[chunk][n][8]  row-direction (softmax over cols j, argmax cols)
//   CP[strip][m][8]  col-direction (softmax over rows i, argmax rows)
__global__ __launch_bounds__(256) void fgram_kernel(
    const unsigned short* __restrict__ SP,
    const float* __restrict__ sf,
    const float* __restrict__ invn,
    int b, int i, int j,
    float* __restrict__ RP,
    float* __restrict__ CP) {
    __shared__ unsigned short smem[6 * 4096];
    __shared__ float sfj[3][256];
    __shared__ float ivj[256];
    __shared__ float sfi[3][128];
    __shared__ float ivi[128];
    __shared__ float RS[2][128][8];   // [wc][row][state]
    __shared__ float CS[2][128][8];   // [wr][col][state]

    const int tid = threadIdx.x;
    const int wid = tid >> 6, lane = tid & 63;
    const int wr = wid >> 1, wc = wid & 1;
    const int g = lane >> 4, ccol = lane & 15;

    const int bid = blockIdx.x;                    // 0..511 (512%8==0 -> bijective)
    const int swz = (bid & 7) * 64 + (bid >> 3);
    const int strip = swz >> 4, chunk = swz & 15;
    const int n0 = strip * 128, m0 = chunk * 256;

    const int gA = b * V_ + i, gB = b * V_ + j;

    // prologue: init RS, stage sf/invn slices
    {
        float* rs = RS[tid >> 7][tid & 127];
        rs[0] = NEG_INF; rs[1] = 0.f; rs[2] = 0.f; rs[3] = 0.f; rs[4] = 0.f;
        rs[5] = NEG_INF; rs[6] = (float)N_; rs[7] = 0.f;
    }
    if (tid < 128) {
        int n = n0 + tid;
        const float* p = sf + (((size_t)(b * N_ + n)) * V_ + i) * C_;
        sfi[0][tid] = p[0]; sfi[1][tid] = p[1]; sfi[2][tid] = p[2];
        ivi[tid] = invn[(size_t)gA * N_ + n];
    }
    {
        int m = m0 + tid;
        const float* p = sf + (((size_t)(b * N_ + m)) * V_ + j) * C_;
        sfj[0][tid] = p[0]; sfj[1][tid] = p[1]; sfj[2][tid] = p[2];
        ivj[tid] = invn[(size_t)gB * N_ + m];
    }

    const int q    = wid * 2;
    const int srow = lane >> 2;
    const int scol = (lane & 3) * 8;
    const int fr   = lane & 15;
    const int fk   = g * 8;

    for (int t = 0; t < 2; ++t) {
        // init CS for this tile
        {
            float* cs = CS[tid >> 7][tid & 127];
            cs[0] = NEG_INF; cs[1] = 0.f; cs[2] = 0.f; cs[3] = 0.f; cs[4] = 0.f;
            cs[5] = NEG_INF; cs[6] = (float)N_; cs[7] = 0.f;
        }
        const int brow0 = m0 + t * 128;

        f32x4 acc[4][4];
        #pragma unroll
        for (int m = 0; m < 4; ++m)
            #pragma unroll
            for (int n = 0; n < 4; ++n) acc[m][n] = (f32x4){0.f, 0.f, 0.f, 0.f};

        for (int k0 = 0; k0 < D_; k0 += 32) {
            __syncthreads();
            #pragma unroll
            for (int pl = 0; pl < 6; ++pl) {
                const unsigned short* src = (pl < 3)
                    ? (SP + (size_t)(gA * 3 + pl) * PLANE)
                    : (SP + (size_t)(gB * 3 + pl - 3) * PLANE);
                const int r0 = (pl < 3) ? n0 : brow0;
                unsigned short* ldsb = smem + pl * 4096 + q * 512;
                #pragma unroll
                for (int c = 0; c < 2; ++c) {
                    const unsigned short* gp =
                        src + ((size_t)(r0 + (q + c) * 16 + srow) << 8) + k0 + scol;
                    gload16(gp, ldsb + c * 512);
                }
            }
            __syncthreads();

            bf16x8 af[3][4];
            #pragma unroll
            for (int l = 0; l < 3; ++l)
                #pragma unroll
                for (int m = 0; m < 4; ++m)
                    af[l][m] = *(const bf16x8*)(smem + l * 4096 +
                                                (wr * 64 + m * 16 + fr) * 32 + fk);
            #pragma unroll
            for (int bl = 0; bl < 3; ++bl) {
                bf16x8 bfr[4];
                #pragma unroll
                for (int n = 0; n < 4; ++n)
                    bfr[n] = *(const bf16x8*)(smem + (3 + bl) * 4096 +
                                              (wc * 64 + n * 16 + fr) * 32 + fk);
                #pragma unroll
                for (int al = 0; al < 3; ++al) {
                    if (al + bl > 2) continue;
                    #pragma unroll
                    for (int m = 0; m < 4; ++m)
                        #pragma unroll
                        for (int n = 0; n < 4; ++n)
                            acc[m][n] = __builtin_amdgcn_mfma_f32_16x16x32_bf16(
                                af[al][m], bfr[n], acc[m][n], 0, 0, 0);
                }
            }
        }

        // ---------------- epilogue: row pass ----------------
        float sj0[4], sj1[4], sj2[4], vj4[4], cgl[4];
        #pragma unroll
        for (int nf = 0; nf < 4; ++nf) {
            int cc = t * 128 + wc * 64 + nf * 16 + ccol;
            sj0[nf] = sfj[0][cc]; sj1[nf] = sfj[1][cc]; sj2[nf] = sfj[2][cc];
            vj4[nf] = ivj[cc];
            cgl[nf] = (float)(m0 + cc);
        }
        #pragma unroll
        for (int m = 0; m < 4; ++m) {
            #pragma unroll
            for (int r = 0; r < 4; ++r) {
                float s0 = acc[m][0][r], s1 = acc[m][1][r];
                float s2 = acc[m][2][r], s3 = acc[m][3][r];
                float mx = fmaxf(fmaxf(s0, s1), fmaxf(s2, s3));
                #pragma unroll
                for (int off = 1; off <= 8; off <<= 1)
                    mx = fmaxf(mx, __shfl_xor(mx, off, 64));
                float e0 = __expf(s0 - mx), e1 = __expf(s1 - mx);
                float e2 = __expf(s2 - mx), e3 = __expf(s3 - mx);
                float sm = e0 + e1 + e2 + e3;
                float a0 = e0 * sj0[0] + e1 * sj0[1] + e2 * sj0[2] + e3 * sj0[3];
                float a1 = e0 * sj1[0] + e1 * sj1[1] + e2 * sj1[2] + e3 * sj1[3];
                float a2 = e0 * sj2[0] + e1 * sj2[1] + e2 * sj2[2] + e3 * sj2[3];
                float bv = s0 * vj4[0], bi = cgl[0];
                { float v = s1 * vj4[1]; if (v > bv || (v == bv && cgl[1] < bi)) { bv = v; bi = cgl[1]; } }
                { float v = s2 * vj4[2]; if (v > bv || (v == bv && cgl[2] < bi)) { bv = v; bi = cgl[2]; } }
                { float v = s3 * vj4[3]; if (v > bv || (v == bv && cgl[3] < bi)) { bv = v; bi = cgl[3]; } }
                #pragma unroll
                for (int off = 1; off <= 8; off <<= 1) {
                    sm += __shfl_xor(sm, off, 64);
                    a0 += __shfl_xor(a0, off, 64);
                    a1 += __shfl_xor(a1, off, 64);
                    a2 += __shfl_xor(a2, off, 64);
                    float obv = __shfl_xor(bv, off, 64);
                    float obi = __shfl_xor(bi, off, 64);
                    if (obv > bv || (obv == bv && obi < bi)) { bv = obv; bi = obi; }
                }
                if (ccol == 0)
                    merge_state(RS[wc][wr * 64 + m * 16 + g * 4 + r], mx, sm, a0, a1, a2, bv, bi);
            }
        }

        // ---------------- epilogue: col pass ----------------
        float cmx[4] = {NEG_INF, NEG_INF, NEG_INF, NEG_INF};
        #pragma unroll
        for (int m = 0; m < 4; ++m)
            #pragma unroll
            for (int nf = 0; nf < 4; ++nf)
                #pragma unroll
                for (int r = 0; r < 4; ++r)
                    cmx[nf] = fmaxf(cmx[nf], acc[m][nf][r]);
        #pragma unroll
        for (int nf = 0; nf < 4; ++nf) {
            cmx[nf] = fmaxf(cmx[nf], __shfl_xor(cmx[nf], 16, 64));
            cmx[nf] = fmaxf(cmx[nf], __shfl_xor(cmx[nf], 32, 64));
        }
        float csm[4] = {0, 0, 0, 0}, cw0[4] = {0, 0, 0, 0};
        float cw1[4] = {0, 0, 0, 0}, cw2[4] = {0, 0, 0, 0};
        float cbv[4] = {NEG_INF, NEG_INF, NEG_INF, NEG_INF};
        float cbi[4] = {(float)N_, (float)N_, (float)N_, (float)N_};
        #pragma unroll
        for (int m = 0; m < 4; ++m) {
            #pragma unroll
            for (int r = 0; r < 4; ++r) {
                int rl = wr * 64 + m * 16 + g * 4 + r;
                float f0 = sfi[0][rl], f1 = sfi[1][rl], f2 = sfi[2][rl], iv = ivi[rl];
                float gn = (float)(n0 + rl);
                #pragma unroll
                for (int nf = 0; nf < 4; ++nf) {
                    float sv = acc[m][nf][r];
                    float e = __expf(sv - cmx[nf]);
                    csm[nf] += e;
                    cw0[nf] = fmaf(e, f0, cw0[nf]);
                    cw1[nf] = fmaf(e, f1, cw1[nf]);
                    cw2[nf] = fmaf(e, f2, cw2[nf]);
                    float v = sv * iv;
                    if (v > cbv[nf] || (v == cbv[nf] && gn < cbi[nf])) { cbv[nf] = v; cbi[nf] = gn; }
                }
            }
        }
        #pragma unroll
        for (int nf = 0; nf < 4; ++nf) {
            #pragma unroll
            for (int off = 16; off <= 32; off <<= 1) {
                csm[nf] += __shfl_xor(csm[nf], off, 64);
                cw0[nf] += __shfl_xor(cw0[nf], off, 64);
                cw1[nf] += __shfl_xor(cw1[nf], off, 64);
                cw2[nf] += __shfl_xor(cw2[nf], off, 64);
                float obv = __shfl_xor(cbv[nf], off, 64);
                float obi = __shfl_xor(cbi[nf], off, 64);
                if (obv > cbv[nf] || (obv == cbv[nf] && obi < cbi[nf])) { cbv[nf] = obv; cbi[nf] = obi; }
            }
            if (g == 0)
                merge_state(CS[wr][wc * 64 + nf * 16 + ccol],
                            cmx[nf], csm[nf], cw0[nf], cw1[nf], cw2[nf], cbv[nf], cbi[nf]);
        }

        __syncthreads();
        // flush col partials for this tile: merge the two wr halves
        if (tid < 128) {
            const float* X = CS[0][tid];
            const float* Y = CS[1][tid];
            float M, S, u0, u1, u2;
            if (X[0] >= Y[0]) {
                float e = __expf(Y[0] - X[0]);
                M = X[0]; S = fmaf(Y[1], e, X[1]);
                u0 = fmaf(Y[2], e, X[2]); u1 = fmaf(Y[3], e, X[3]); u2 = fmaf(Y[4], e, X[4]);
            } else {
                float e = __expf(X[0] - Y[0]);
                M = Y[0]; S = fmaf(X[1], e, Y[1]);
                u0 = fmaf(X[2], e, Y[2]); u1 = fmaf(X[3], e, Y[3]); u2 = fmaf(X[4], e, Y[4]);
            }
            float av = X[5], ai = X[6];
            if (Y[5] > av || (Y[5] == av && Y[6] < ai)) { av = Y[5]; ai = Y[6]; }
            float* o = CP + ((size_t)strip * N_ + m0 + t * 128 + tid) * 8;
            *(float4*)o       = make_float4(M, S, u0, u1);
            *(float4*)(o + 4) = make_float4(u2, av, ai, 0.f);
        }
        __syncthreads();
    }

    // flush row partials: merge the two wc halves
    if (tid < 128) {
        const float* X = RS[0][tid];
        const float* Y = RS[1][tid];
        float M, S, u0, u1, u2;
        if (X[0] >= Y[0]) {
            float e = __expf(Y[0] - X[0]);
            M = X[0]; S = fmaf(Y[1], e, X[1]);
            u0 = fmaf(Y[2], e, X[2]); u1 = fmaf(Y[3], e, X[3]); u2 = fmaf(Y[4], e, X[4]);
        } else {
            float e = __expf(X[0] - Y[0]);
            M = Y[0]; S = fmaf(X[1], e, Y[1]);
            u0 = fmaf(X[2], e, Y[2]); u1 = fmaf(X[3], e, Y[3]); u2 = fmaf(X[4], e, Y[4]);
        }
        float av = X[5], ai = X[6];
        if (Y[5] > av || (Y[5] == av && Y[6] < ai)) { av = Y[5]; ai = Y[6]; }
        float* o = RP + ((size_t)chunk * N_ + n0 + tid) * 8;
        *(float4*)o       = make_float4(M, S, u0, u1);
        *(float4*)(o + 4) = make_float4(u2, av, ai, 0.f);
    }
}

// ---------------------------------------------------------------------------
// Combine partials for all 12 units x both directions -> soft + argmax indices.
// blockIdx.y = unit u (p*2+b); blockIdx.x: 0..15 rows, 16..31 cols.
__global__ __launch_bounds__(256) void comb_kernel(const float* __restrict__ PT,
                                                   float* __restrict__ soft,
                                                   int* __restrict__ idxbuf) {
    const int pi[6] = {0, 0, 0, 1, 1, 2}, pj[6] = {1, 2, 3, 2, 3, 3};
    int u = blockIdx.y, p = u >> 1, b = u & 1;
    int i = pi[p], j = pj[p];
    int x = blockIdx.x;
    int idx = (x & 15) * 256 + threadIdx.x;
    const size_t unit = (size_t)u * 48 * N_ * 8;
    const float* base;
    int K, dd, which;
    if (x < 16) { base = PT + unit + (size_t)idx * 8;                       K = 16; dd = (i * 3 + (j - 1)) * 2 + b; which = 0; }
    else        { base = PT + unit + (size_t)16 * N_ * 8 + (size_t)idx * 8; K = 32; dd = (j * 3 + i) * 2 + b;       which = 1; }

    float4 a = *(const float4*)base;
    float4 b4 = *(const float4*)(base + 4);
    float M = a.x, S = a.y, w0 = a.z, w1 = a.w, w2 = b4.x, av = b4.y, ai = b4.z;
    for (int k = 1; k < K; ++k) {
        const float* qp = base + (size_t)k * N_ * 8;
        float4 c = *(const float4*)qp;
        float4 d = *(const float4*)(qp + 4);
        if (c.x > M) {
            float e = __expf(M - c.x);
            M = c.x;
            S  = fmaf(S,  e, c.y);
            w0 = fmaf(w0, e, c.z);
            w1 = fmaf(w1, e, c.w);
            w2 = fmaf(w2, e, d.x);
        } else {
            float e = __expf(c.x - M);
            S  = fmaf(c.y, e, S);
            w0 = fmaf(c.z, e, w0);
            w1 = fmaf(c.w, e, w1);
            w2 = fmaf(d.x, e, w2);
        }
        if (d.y > av || (d.y == av && d.z < ai)) { av = d.y; ai = d.z; }
    }
    float inv = 1.0f / S;
    float* so = soft + ((size_t)dd * N_ + idx) * 3;
    so[0] = w0 * inv; so[1] = w1 * inv; so[2] = w2 * inv;
    idxbuf[((size_t)u * 2 + which) * N_ + idx] = (int)ai;
}

// ---------------------------------------------------------------------------
__global__ __launch_bounds__(256) void mutualB_kernel(const int* __restrict__ idxbuf,
                                                      int* __restrict__ hm) {
    int u = blockIdx.y;
    int n = blockIdx.x * 256 + threadIdx.x;
    int a = idxbuf[((size_t)u * 2 + 0) * N_ + n];
    int ok = (idxbuf[((size_t)u * 2 + 1) * N_ + a] == n) ? 1 : 0;
    unsigned long long m = __ballot(ok);
    if ((threadIdx.x & 63) == 0 && m != 0ull) atomicOr(&hm[u], 1);
}

// ---------------------------------------------------------------------------
// Z GEMM (bf16x6 emulated fp32), unchanged m97-style body
template<bool BIAS>
__device__ __forceinline__ void mm6_body(
    const unsigned short* __restrict__ A0, const unsigned short* __restrict__ A1,
    const unsigned short* __restrict__ A2,
    const unsigned short* __restrict__ B0, const unsigned short* __restrict__ B1,
    const unsigned short* __restrict__ B2,
    int bx, int by,
    float* __restrict__ Cout, const float* __restrict__ bias, int ldc,
    unsigned short* smem) {
    const int tid = threadIdx.x;
    const int wid = tid >> 6, lane = tid & 63;
    const int wr = wid >> 1, wc = wid & 1;
    const int arow0 = bx * 128, brow0 = by * 128;

    f32x4 acc[4][4];
    #pragma unroll
    for (int m = 0; m < 4; ++m)
        #pragma unroll
        for (int n = 0; n < 4; ++n) acc[m][n] = (f32x4){0.f, 0.f, 0.f, 0.f};

    const unsigned short* Asrc[3] = {A0, A1, A2};
    const unsigned short* Bsrc[3] = {B0, B1, B2};
    const int q    = wid * 2;
    const int srow = lane >> 2;
    const int scol = (lane & 3) * 8;
    const int fr = lane & 15;
    const int fk = (lane >> 4) * 8;

    for (int k0 = 0; k0 < D_; k0 += 32) {
        __syncthreads();
        #pragma unroll
        for (int s = 0; s < 6; ++s) {
            const unsigned short* src = (s < 3) ? Asrc[s] : Bsrc[s - 3];
            const int r0 = (s < 3) ? arow0 : brow0;
            unsigned short* ldsb = smem + s * 4096 + q * 512;
            #pragma unroll
            for (int c = 0; c < 2; ++c) {
                const unsigned short* gp =
                    src + ((size_t)(r0 + (q + c) * 16 + srow) << 8) + k0 + scol;
                gload16(gp, ldsb + c * 512);
            }
        }
        __syncthreads();
        bf16x8 af[3][4];
        #pragma unroll
        for (int l = 0; l < 3; ++l)
            #pragma unroll
            for (int m = 0; m < 4; ++m)
                af[l][m] = *(const bf16x8*)(smem + l * 4096 +
                                            (wr * 64 + m * 16 + fr) * 32 + fk);
        #pragma unroll
        for (int bl = 0; bl < 3; ++bl) {
            bf16x8 bfr[4];
            #pragma unroll
            for (int n = 0; n < 4; ++n)
                bfr[n] = *(const bf16x8*)(smem + (3 + bl) * 4096 +
                                          (wc * 64 + n * 16 + fr) * 32 + fk);
            #pragma unroll
            for (int al = 0; al < 3; ++al) {
                if (al + bl > 2) continue;
                #pragma unroll
                for (int m = 0; m < 4; ++m)
                    #pragma unroll
                    for (int n = 0; n < 4; ++n)
                        acc[m][n] = __builtin_amdgcn_mfma_f32_16x16x32_bf16(
                            af[al][m], bfr[n], acc[m][n], 0, 0, 0);
            }
        }
    }
    const int crow = (lane >> 4) * 4;
    const int ccol = lane & 15;
    #pragma unroll
    for (int m = 0; m < 4; ++m) {
        const int gr = arow0 + wr * 64 + m * 16 + crow;
        #pragma unroll
        for (int n = 0; n < 4; ++n) {
            const int gc = brow0 + wc * 64 + n * 16 + ccol;
            f32x4 v = acc[m][n];
            float bv = BIAS ? bias[gc] : 0.0f;
            #pragma unroll
            for (int r = 0; r < 4; ++r)
                Cout[(size_t)(gr + r) * ldc + gc] = v[r] + bv;
        }
    }
}

__global__ __launch_bounds__(256) void zmm6_kernel(const unsigned short* __restrict__ SP,
                                                   const unsigned short* __restrict__ W1T,
                                                   const float* __restrict__ b1,
                                                   float* __restrict__ Z) {
    __shared__ unsigned short smem[6 * 4096];
    int bv = blockIdx.z;
    mm6_body<true>(SP + (size_t)(bv * 3 + 0) * PLANE,
                   SP + (size_t)(bv * 3 + 1) * PLANE,
                   SP + (size_t)(bv * 3 + 2) * PLANE,
                   W1T, W1T + WPLANE, W1T + 2 * WPLANE,
                   blockIdx.x, blockIdx.y,
                   Z + (size_t)bv * N_ * H_, b1, H_, smem);
}

// ---------------------------------------------------------------------------
__global__ __launch_bounds__(512) void tcode_kernel(const float* __restrict__ T,
                                                    const float* __restrict__ Wt,
                                                    float* __restrict__ tcode) {
    int dp = blockIdx.x;
    int i = dp / 3, rem = dp % 3;
    int j = rem + (rem >= i ? 1 : 0);
    int h = threadIdx.x;
    float acc = 0.0f;
    #pragma unroll
    for (int k = 0; k < 16; k++) acc = fmaf(T[i * 16 + k], Wt[k * H_ + h], acc);
    #pragma unroll
    for (int k = 0; k < 16; k++) acc = fmaf(T[j * 16 + k], Wt[(16 + k) * H_ + h], acc);
    tcode[dp * H_ + h] = acc;
}

// ---------------------------------------------------------------------------
__global__ __launch_bounds__(256) void loss_kernel(const float* __restrict__ Z,
                                                   const float* __restrict__ tcode,
                                                   const float* __restrict__ soft,
                                                   const float* __restrict__ W2,
                                                   const float* __restrict__ b2,
                                                   float* __restrict__ loss_sum) {
    int dd = blockIdx.y;
    int dp = dd >> 1, b = dd & 1;
    int i = dp / 3;
    const float* tc = tcode + (size_t)dp * H_;
    const float* zbase = Z + (size_t)((b * V_ + i) * N_) * H_;
    const float* softb = soft + (size_t)dd * N_ * C_;
    int tid = threadIdx.x;
    int wid = tid >> 6, lane = tid & 63;
    __shared__ float wsum[4];
    float sse_acc = 0.0f;
    float4 t1 = *(const float4*)(tc + lane * 4);
    float4 t2 = *(const float4*)(tc + 256 + lane * 4);
    for (int rr = wid; rr < 64; rr += 4) {
        int n = blockIdx.x * 64 + rr;
        const float* zp = zbase + (size_t)n * H_;
        float4 z1 = *(const float4*)(zp + lane * 4);
        float4 z2 = *(const float4*)(zp + 256 + lane * 4);
        float pre[8] = {z1.x + t1.x, z1.y + t1.y, z1.z + t1.z, z1.w + t1.w,
                        z2.x + t2.x, z2.y + t2.y, z2.z + t2.z, z2.w + t2.w};
        float c0 = 0.f, c1 = 0.f, c2 = 0.f;
        int h1 = lane * 4, h2 = 256 + lane * 4;
        #pragma unroll
        for (int q = 0; q < 8; q++) {
            float rv = fmaxf(pre[q], 0.0f);
            int h = (q < 4) ? (h1 + q) : (h2 + q - 4);
            c0 = fmaf(rv, W2[h * 3 + 0], c0);
            c1 = fmaf(rv, W2[h * 3 + 1], c1);
            c2 = fmaf(rv, W2[h * 3 + 2], c2);
        }
        #pragma unroll
        for (int off = 32; off >= 1; off >>= 1) {
            c0 += __shfl_xor(c0, off, 64);
            c1 += __shfl_xor(c1, off, 64);
            c2 += __shfl_xor(c2, off, 64);
        }
        if (lane == 0) {
            float e0 = c0 + b2[0] - softb[(size_t)n * C_ + 0];
            float e1 = c1 + b2[1] - softb[(size_t)n * C_ + 1];
            float e2 = c2 + b2[2] - softb[(size_t)n * C_ + 2];
            sse_acc += e0 * e0 + e1 * e1 + e2 * e2;
        }
    }
    if (lane == 0) wsum[wid] = sse_acc;
    __syncthreads();
    if (tid == 0) {
        atomicAdd(&loss_sum[dd], wsum[0] + wsum[1] + wsum[2] + wsum[3]);
    }
}

// ---------------------------------------------------------------------------
__global__ __launch_bounds__(64) void final_kernel(const float* __restrict__ loss_sum,
                                                   const int* __restrict__ hm,
                                                   float* __restrict__ out) {
    if (threadIdx.x != 0 || blockIdx.x != 0) return;
    float lt = 0.0f, cnt = 0.0f;
    for (int dp = 0; dp < 12; dp++) {
        int i = dp / 3, rem = dp % 3;
        int j = rem + (rem >= i ? 1 : 0);
        int a = i < j ? i : j, c = i < j ? j : i;
        int p = a * 3 - (a * (a - 1)) / 2 + (c - a - 1);
        for (int b = 0; b < 2; b++) {
            if (hm[p * 2 + b]) {
                lt += loss_sum[dp * 2 + b] * (1.0f / ((float)N_ * (float)C_));
                cnt += 1.0f;
            }
        }
    }
    out[0] = (cnt > 0.0f) ? (lt / cnt) : 0.0f;
}

// ---------------------------------------------------------------------------
extern "C" void kernel_launch(void* const* d_in, const int* in_sizes, int n_in,
                              void* d_out, int out_size, void* d_ws, size_t ws_size,
                              hipStream_t stream) {
    const float* desc = (const float*)d_in[0];
    const float* sf   = (const float*)d_in[1];
    const float* T    = (const float*)d_in[2];
    const float* W1   = (const float*)d_in[3];
    const float* b1   = (const float*)d_in[4];
    const float* Wt   = (const float*)d_in[5];
    const float* W2   = (const float*)d_in[6];
    const float* b2   = (const float*)d_in[7];
    float* out = (float*)d_out;

    // workspace layout
    const size_t NM = (size_t)N_ * N_;
    unsigned short* SP  = (unsigned short*)d_ws;          // 24*PLANE (50.3MB)
    unsigned short* W1T = SP + (size_t)24 * PLANE;        // 3*WPLANE
    float* w     = (float*)(W1T + (size_t)3 * WPLANE);
    float* Z     = w;                                     // NM (67MB)
    float* PT    = w + NM;                                // 12 * 48 * N_ * 8 (75.5MB)
    float* invn  = PT + (size_t)12 * 48 * N_ * 8;         // 32768
    float* tcode = invn + (size_t)B_ * V_ * N_;           // 6144
    float* soft  = tcode + 12 * H_;                       // 294912
    int*   idxbuf = (int*)(soft + (size_t)12 * B_ * N_ * C_); // 12*2*N
    float* loss_sum = (float*)(idxbuf + (size_t)12 * 2 * N_); // 24
    int*   hm    = (int*)(loss_sum + 24);                 // 12

    zero_accum_kernel<<<1, 64, 0, stream>>>(loss_sum, hm);
    split_kernel<<<8192, 256, 0, stream>>>(desc, SP);
    w1split_kernel<<<512, 256, 0, stream>>>(W1, W1T);
    norms_kernel<<<(B_ * V_ * N_) / 4, 256, 0, stream>>>(desc, invn);
    tcode_kernel<<<12, 512, 0, stream>>>(T, Wt, tcode);

    const int pairs[6][2] = {{0, 1}, {0, 2}, {0, 3}, {1, 2}, {1, 3}, {2, 3}};
    for (int p = 0; p < 6; p++) {
        int i = pairs[p][0], j = pairs[p][1];
        for (int b = 0; b < 2; b++) {
            int u = p * 2 + b;
            float* RPu = PT + (size_t)u * 48 * N_ * 8;
            float* CPu = RPu + (size_t)16 * N_ * 8;
            fgram_kernel<<<512, 256, 0, stream>>>(SP, sf, invn, b, i, j, RPu, CPu);
        }
    }

    zmm6_kernel<<<dim3(32, 4, 8), 256, 0, stream>>>(SP, W1T, b1, Z);
    comb_kernel<<<dim3(32, 12), 256, 0, stream>>>(PT, soft, idxbuf);
    mutualB_kernel<<<dim3(16, 12), 256, 0, stream>>>(idxbuf, hm);
    loss_kernel<<<dim3(64, 24), 256, 0, stream>>>(Z, tcode, soft, W2, b2, loss_sum);
    final_kernel<<<1, 64, 0, stream>>>(loss_sum, hm, out);
}

// Round 7
// 1605.690 us; speedup vs baseline: 1.1587x; 1.1587x over previous
//
#include <hip/hip_runtime.h>
#include <cstdint>
#include <cstddef>

// Problem constants
#define N_ 4096
#define B_ 2
#define V_ 4
#define D_ 256
#define C_ 3
#define H_ 512

#define PLANE 1048576   // N_*D_ elements per split plane
#define WPLANE 131072   // H_*D_ elements per W1T split plane
#define NEG_INF (-__builtin_inff())

typedef __attribute__((ext_vector_type(8))) short bf16x8;   // 8 bf16 in 4 VGPRs
typedef __attribute__((ext_vector_type(4))) float f32x4;

// ---------------------------------------------------------------------------
__device__ __forceinline__ void gload16(const void* g, void* l) {
    __builtin_amdgcn_global_load_lds(
        (const __attribute__((address_space(1))) void*)g,
        (__attribute__((address_space(3))) void*)l,
        16, 0, 0);
}

// RNE float->bf16
__device__ __forceinline__ unsigned short f2bf(float x) {
    unsigned u = __builtin_bit_cast(unsigned, x);
    u += 0x7FFFu + ((u >> 16) & 1u);
    return (unsigned short)(u >> 16);
}
__device__ __forceinline__ float bf2f(unsigned short h) {
    unsigned u = ((unsigned)h) << 16;
    return __builtin_bit_cast(float, u);
}
__device__ __forceinline__ void split3(float x, unsigned short& h, unsigned short& m,
                                       unsigned short& l) {
    h = f2bf(x);
    float r = x - bf2f(h);
    m = f2bf(r);
    l = f2bf(r - bf2f(m));
}

// Online-softmax + argmax state merge. st = {M, S, w0, w1, w2, av, ai, ...}
__device__ __forceinline__ void merge_state(float* st, float M2, float S2,
                                            float w0, float w1, float w2,
                                            float av2, float ai2) {
    float M1 = st[0];
    if (M2 > M1) {
        float e = __expf(M1 - M2);     // M1=-inf -> e=0, clean
        st[0] = M2;
        st[1] = fmaf(st[1], e, S2);
        st[2] = fmaf(st[2], e, w0);
        st[3] = fmaf(st[3], e, w1);
        st[4] = fmaf(st[4], e, w2);
    } else {
        float e = __expf(M2 - M1);
        st[1] = fmaf(S2, e, st[1]);
        st[2] = fmaf(w0, e, st[2]);
        st[3] = fmaf(w1, e, st[3]);
        st[4] = fmaf(w2, e, st[4]);
    }
    if (av2 > st[5] || (av2 == st[5] && ai2 < st[6])) { st[5] = av2; st[6] = ai2; }
}

// ---------------------------------------------------------------------------
__global__ __launch_bounds__(64) void zero_accum_kernel(float* loss_sum, int* hm) {
    int t = threadIdx.x;
    if (t < 24) loss_sum[t] = 0.0f;
    if (t < 12) hm[t] = 0;
}

// ---------------------------------------------------------------------------
// Split desc fp32 -> 3 bf16 planes per (b,v):  SP[(bv*3+l)][n][d]
__global__ __launch_bounds__(256) void split_kernel(const float* __restrict__ desc,
                                                    unsigned short* __restrict__ SP) {
    int t = blockIdx.x * 256 + threadIdx.x;
    int d4 = t & 63;
    int v  = (t >> 6) & 3;
    int n  = (t >> 8) & 4095;
    int b  = t >> 20;
    const float4 x = *(const float4*)(desc + (((size_t)(b * N_ + n) * V_ + v) << 8) + d4 * 4);
    ushort4 hv, mv, lv;
    split3(x.x, hv.x, mv.x, lv.x);
    split3(x.y, hv.y, mv.y, lv.y);
    split3(x.z, hv.z, mv.z, lv.z);
    split3(x.w, hv.w, mv.w, lv.w);
    size_t base = (size_t)((b * V_ + v) * 3) * PLANE + n * D_ + d4 * 4;
    *(ushort4*)(SP + base)              = hv;
    *(ushort4*)(SP + base + PLANE)      = mv;
    *(ushort4*)(SP + base + 2 * PLANE)  = lv;
}

// W1 [D][H] -> transposed split planes W1T[l][h][k]
__global__ __launch_bounds__(256) void w1split_kernel(const float* __restrict__ W1,
                                                      unsigned short* __restrict__ W1T) {
    int t = blockIdx.x * 256 + threadIdx.x;
    int h = t & 511;
    int k = t >> 9;
    float x = W1[(size_t)k * H_ + h];
    unsigned short hv, mv, lv;
    split3(x, hv, mv, lv);
    size_t o = (size_t)h * D_ + k;
    W1T[o] = hv; W1T[o + WPLANE] = mv; W1T[o + 2 * WPLANE] = lv;
}

// ---------------------------------------------------------------------------
__global__ __launch_bounds__(256) void norms_kernel(const float* __restrict__ desc,
                                                    float* __restrict__ invn) {
    int gw   = (blockIdx.x * 256 + threadIdx.x) >> 6;
    int lane = threadIdx.x & 63;
    int bv = gw >> 12;
    int n  = gw & (N_ - 1);
    int b  = bv >> 2, v = bv & 3;
    const float* p = desc + ((size_t)(b * N_ + n) * V_ + v) * D_;
    float4 x = *(const float4*)(p + lane * 4);
    float s = x.x * x.x + x.y * x.y + x.z * x.z + x.w * x.w;
    #pragma unroll
    for (int off = 32; off >= 1; off >>= 1) s += __shfl_xor(s, off, 64);
    if (lane == 0) invn[gw] = 1.0f / fmaxf(sqrtf(s), 1e-12f);
}

// ---------------------------------------------------------------------------
// FUSED gram + row/col online-softmax/argmax reductions (never materializes S).
// Epilogue v2: stage fp32 tile halves into LDS, thread-parallel scans
// (no long shuffle chains).  Emits per-block partial states:
//   RP[chunk][n][8]  row-direction (softmax over cols j, argmax cols)
//   CP[strip][m][8]  col-direction (softmax over rows i, argmax rows)
__global__ __launch_bounds__(256) void fgram_kernel(
    const unsigned short* __restrict__ SP,
    const float* __restrict__ sf,
    const float* __restrict__ invn,
    int b, int i, int j,
    float* __restrict__ RP,
    float* __restrict__ CP) {
    __shared__ __align__(16) unsigned char smraw[49152];  // bf16 staging / f32 tile
    __shared__ float4 sfj4[256];   // {sf0,sf1,sf2,invn} per chunk col
    __shared__ float4 sfi4[128];   // {sf0,sf1,sf2,invn} per strip row
    __shared__ float RS[128][9];   // row states (pad 9 -> conflict-free)
    __shared__ float CS[128][9];   // col states (per tile)
    unsigned short* stage = (unsigned short*)smraw;
    float* tile = (float*)smraw;   // [64 rows][132] per half

    const int tid = threadIdx.x;
    const int wid = tid >> 6, lane = tid & 63;
    const int wr = wid >> 1, wc = wid & 1;
    const int g = lane >> 4, ccol = lane & 15;

    const int bid = blockIdx.x;                    // 0..511 (512%8==0 -> bijective)
    const int swz = (bid & 7) * 64 + (bid >> 3);
    const int strip = swz >> 4, chunk = swz & 15;
    const int n0 = strip * 128, m0 = chunk * 256;

    const int gA = b * V_ + i, gB = b * V_ + j;

    // prologue: init RS, stage sf/invn slices
    if (tid < 128) {
        float* rs = RS[tid];
        rs[0] = NEG_INF; rs[1] = 0.f; rs[2] = 0.f; rs[3] = 0.f; rs[4] = 0.f;
        rs[5] = NEG_INF; rs[6] = (float)N_;
        int n = n0 + tid;
        const float* p = sf + (((size_t)(b * N_ + n)) * V_ + i) * C_;
        sfi4[tid] = make_float4(p[0], p[1], p[2], invn[(size_t)gA * N_ + n]);
    }
    {
        int m = m0 + tid;
        const float* p = sf + (((size_t)(b * N_ + m)) * V_ + j) * C_;
        sfj4[tid] = make_float4(p[0], p[1], p[2], invn[(size_t)gB * N_ + m]);
    }

    const int q    = wid * 2;
    const int srow = lane >> 2;
    const int scol = (lane & 3) * 8;
    const int fr   = lane & 15;
    const int fk   = g * 8;

    for (int t = 0; t < 2; ++t) {
        if (tid < 128) {
            float* cs = CS[tid];
            cs[0] = NEG_INF; cs[1] = 0.f; cs[2] = 0.f; cs[3] = 0.f; cs[4] = 0.f;
            cs[5] = NEG_INF; cs[6] = (float)N_;
        }
        const int brow0 = m0 + t * 128;

        f32x4 acc[4][4];
        #pragma unroll
        for (int m = 0; m < 4; ++m)
            #pragma unroll
            for (int n = 0; n < 4; ++n) acc[m][n] = (f32x4){0.f, 0.f, 0.f, 0.f};

        for (int k0 = 0; k0 < D_; k0 += 32) {
            __syncthreads();
            #pragma unroll
            for (int pl = 0; pl < 6; ++pl) {
                const unsigned short* src = (pl < 3)
                    ? (SP + (size_t)(gA * 3 + pl) * PLANE)
                    : (SP + (size_t)(gB * 3 + pl - 3) * PLANE);
                const int r0 = (pl < 3) ? n0 : brow0;
                unsigned short* ldsb = stage + pl * 4096 + q * 512;
                #pragma unroll
                for (int c = 0; c < 2; ++c) {
                    const unsigned short* gp =
                        src + ((size_t)(r0 + (q + c) * 16 + srow) << 8) + k0 + scol;
                    gload16(gp, ldsb + c * 512);
                }
            }
            __syncthreads();

            bf16x8 af[3][4];
            #pragma unroll
            for (int l = 0; l < 3; ++l)
                #pragma unroll
                for (int m = 0; m < 4; ++m)
                    af[l][m] = *(const bf16x8*)(stage + l * 4096 +
                                                (wr * 64 + m * 16 + fr) * 32 + fk);
            #pragma unroll
            for (int bl = 0; bl < 3; ++bl) {
                bf16x8 bfr[4];
                #pragma unroll
                for (int n = 0; n < 4; ++n)
                    bfr[n] = *(const bf16x8*)(stage + (3 + bl) * 4096 +
                                              (wc * 64 + n * 16 + fr) * 32 + fk);
                #pragma unroll
                for (int al = 0; al < 3; ++al) {
                    if (al + bl > 2) continue;
                    #pragma unroll
                    for (int m = 0; m < 4; ++m)
                        #pragma unroll
                        for (int n = 0; n < 4; ++n)
                            acc[m][n] = __builtin_amdgcn_mfma_f32_16x16x32_bf16(
                                af[al][m], bfr[n], acc[m][n], 0, 0, 0);
                }
            }
        }

        // -------- epilogue v2: LDS-staged thread-parallel reductions --------
        for (int half = 0; half < 2; ++half) {
            __syncthreads();   // staging buffer free / previous scan done
            if (wr == half) {
                #pragma unroll
                for (int m = 0; m < 4; ++m)
                    #pragma unroll
                    for (int nf = 0; nf < 4; ++nf) {
                        int c = wc * 64 + nf * 16 + ccol;
                        int rb = m * 16 + g * 4;
                        #pragma unroll
                        for (int r = 0; r < 4; ++r)
                            tile[(rb + r) * 132 + c] = acc[m][nf][r];
                    }
            }
            __syncthreads();

            // ---- row scan: 64 rows x 4 interleaved quarters ----
            {
                const int row = tid >> 2, qq = tid & 3;
                const float* rp = tile + row * 132;
                const int cb = t * 128;
                float mx = NEG_INF, bv = NEG_INF, bif = (float)N_;
                for (int ii = 0; ii < 32; ++ii) {
                    int c = (ii << 2) + qq;
                    float s = rp[c];
                    mx = fmaxf(mx, s);
                    float vv = s * sfj4[cb + c].w;
                    float gi = (float)(m0 + cb + c);
                    if (vv > bv || (vv == bv && gi < bif)) { bv = vv; bif = gi; }
                }
                float sum = 0.f, w0 = 0.f, w1 = 0.f, w2 = 0.f;
                for (int ii = 0; ii < 32; ++ii) {
                    int c = (ii << 2) + qq;
                    float s = rp[c];
                    float e = __expf(s - mx);
                    float4 sp = sfj4[cb + c];
                    sum += e;
                    w0 = fmaf(e, sp.x, w0); w1 = fmaf(e, sp.y, w1); w2 = fmaf(e, sp.z, w2);
                }
                #pragma unroll
                for (int off = 1; off <= 2; off <<= 1) {
                    float oM = __shfl_xor(mx, off, 64);
                    float oS = __shfl_xor(sum, off, 64);
                    float o0 = __shfl_xor(w0, off, 64);
                    float o1 = __shfl_xor(w1, off, 64);
                    float o2 = __shfl_xor(w2, off, 64);
                    float ob = __shfl_xor(bv, off, 64);
                    float oi = __shfl_xor(bif, off, 64);
                    float nM = fmaxf(mx, oM);
                    float e1 = __expf(mx - nM), e2 = __expf(oM - nM);
                    sum = sum * e1 + oS * e2;
                    w0 = w0 * e1 + o0 * e2;
                    w1 = w1 * e1 + o1 * e2;
                    w2 = w2 * e1 + o2 * e2;
                    mx = nM;
                    if (ob > bv || (ob == bv && oi < bif)) { bv = ob; bif = oi; }
                }
                if (qq == 0)
                    merge_state(RS[half * 64 + row], mx, sum, w0, w1, w2, bv, bif);
            }

            // ---- col scan: 128 cols x 2 row-halves ----
            {
                const int c = tid >> 1, h = tid & 1;
                const float* cp = tile + (h * 32) * 132 + c;
                const int rb = half * 64 + h * 32;
                float mx = NEG_INF, bv = NEG_INF, bif = (float)N_;
                for (int ii = 0; ii < 32; ++ii) {
                    float s = cp[ii * 132];
                    mx = fmaxf(mx, s);
                    float vv = s * sfi4[rb + ii].w;
                    float gi = (float)(n0 + rb + ii);
                    if (vv > bv || (vv == bv && gi < bif)) { bv = vv; bif = gi; }
                }
                float sum = 0.f, w0 = 0.f, w1 = 0.f, w2 = 0.f;
                for (int ii = 0; ii < 32; ++ii) {
                    float s = cp[ii * 132];
                    float e = __expf(s - mx);
                    float4 sp = sfi4[rb + ii];
                    sum += e;
                    w0 = fmaf(e, sp.x, w0); w1 = fmaf(e, sp.y, w1); w2 = fmaf(e, sp.z, w2);
                }
                {
                    float oM = __shfl_xor(mx, 1, 64);
                    float oS = __shfl_xor(sum, 1, 64);
                    float o0 = __shfl_xor(w0, 1, 64);
                    float o1 = __shfl_xor(w1, 1, 64);
                    float o2 = __shfl_xor(w2, 1, 64);
                    float ob = __shfl_xor(bv, 1, 64);
                    float oi = __shfl_xor(bif, 1, 64);
                    float nM = fmaxf(mx, oM);
                    float e1 = __expf(mx - nM), e2 = __expf(oM - nM);
                    sum = sum * e1 + oS * e2;
                    w0 = w0 * e1 + o0 * e2;
                    w1 = w1 * e1 + o1 * e2;
                    w2 = w2 * e1 + o2 * e2;
                    mx = nM;
                    if (ob > bv || (ob == bv && oi < bif)) { bv = ob; bif = oi; }
                    if (h == 0)
                        merge_state(CS[c], mx, sum, w0, w1, w2, bv, bif);
                }
            }
        }

        __syncthreads();
        // flush col partials for this tile
        if (tid < 128) {
            const float* cs = CS[tid];
            float* o = CP + ((size_t)strip * N_ + m0 + t * 128 + tid) * 8;
            *(float4*)o       = make_float4(cs[0], cs[1], cs[2], cs[3]);
            *(float4*)(o + 4) = make_float4(cs[4], cs[5], cs[6], 0.f);
        }
    }

    // flush row partials
    if (tid < 128) {
        const float* rs = RS[tid];
        float* o = RP + ((size_t)chunk * N_ + n0 + tid) * 8;
        *(float4*)o       = make_float4(rs[0], rs[1], rs[2], rs[3]);
        *(float4*)(o + 4) = make_float4(rs[4], rs[5], rs[6], 0.f);
    }
}

// ---------------------------------------------------------------------------
// Combine partials for all 12 units x both directions -> soft + argmax indices.
// blockIdx.y = unit u (p*2+b); blockIdx.x: 0..15 rows, 16..31 cols.
__global__ __launch_bounds__(256) void comb_kernel(const float* __restrict__ PT,
                                                   float* __restrict__ soft,
                                                   int* __restrict__ idxbuf) {
    const int pi[6] = {0, 0, 0, 1, 1, 2}, pj[6] = {1, 2, 3, 2, 3, 3};
    int u = blockIdx.y, p = u >> 1, b = u & 1;
    int i = pi[p], j = pj[p];
    int x = blockIdx.x;
    int idx = (x & 15) * 256 + threadIdx.x;
    const size_t unit = (size_t)u * 48 * N_ * 8;
    const float* base;
    int K, dd, which;
    if (x < 16) { base = PT + unit + (size_t)idx * 8;                       K = 16; dd = (i * 3 + (j - 1)) * 2 + b; which = 0; }
    else        { base = PT + unit + (size_t)16 * N_ * 8 + (size_t)idx * 8; K = 32; dd = (j * 3 + i) * 2 + b;       which = 1; }

    float4 a = *(const float4*)base;
    float4 b4 = *(const float4*)(base + 4);
    float M = a.x, S = a.y, w0 = a.z, w1 = a.w, w2 = b4.x, av = b4.y, ai = b4.z;
    for (int k = 1; k < K; ++k) {
        const float* qp = base + (size_t)k * N_ * 8;
        float4 c = *(const float4*)qp;
        float4 d = *(const float4*)(qp + 4);
        if (c.x > M) {
            float e = __expf(M - c.x);
            M = c.x;
            S  = fmaf(S,  e, c.y);
            w0 = fmaf(w0, e, c.z);
            w1 = fmaf(w1, e, c.w);
            w2 = fmaf(w2, e, d.x);
        } else {
            float e = __expf(c.x - M);
            S  = fmaf(c.y, e, S);
            w0 = fmaf(c.z, e, w0);
            w1 = fmaf(c.w, e, w1);
            w2 = fmaf(d.x, e, w2);
        }
        if (d.y > av || (d.y == av && d.z < ai)) { av = d.y; ai = d.z; }
    }
    float inv = 1.0f / S;
    float* so = soft + ((size_t)dd * N_ + idx) * 3;
    so[0] = w0 * inv; so[1] = w1 * inv; so[2] = w2 * inv;
    idxbuf[((size_t)u * 2 + which) * N_ + idx] = (int)ai;
}

// ---------------------------------------------------------------------------
__global__ __launch_bounds__(256) void mutualB_kernel(const int* __restrict__ idxbuf,
                                                      int* __restrict__ hm) {
    int u = blockIdx.y;
    int n = blockIdx.x * 256 + threadIdx.x;
    int a = idxbuf[((size_t)u * 2 + 0) * N_ + n];
    int ok = (idxbuf[((size_t)u * 2 + 1) * N_ + a] == n) ? 1 : 0;
    unsigned long long m = __ballot(ok);
    if ((threadIdx.x & 63) == 0 && m != 0ull) atomicOr(&hm[u], 1);
}

// ---------------------------------------------------------------------------
// Z GEMM (bf16x6 emulated fp32), unchanged m97-style body
template<bool BIAS>
__device__ __forceinline__ void mm6_body(
    const unsigned short* __restrict__ A0, const unsigned short* __restrict__ A1,
    const unsigned short* __restrict__ A2,
    const unsigned short* __restrict__ B0, const unsigned short* __restrict__ B1,
    const unsigned short* __restrict__ B2,
    int bx, int by,
    float* __restrict__ Cout, const float* __restrict__ bias, int ldc,
    unsigned short* smem) {
    const int tid = threadIdx.x;
    const int wid = tid >> 6, lane = tid & 63;
    const int wr = wid >> 1, wc = wid & 1;
    const int arow0 = bx * 128, brow0 = by * 128;

    f32x4 acc[4][4];
    #pragma unroll
    for (int m = 0; m < 4; ++m)
        #pragma unroll
        for (int n = 0; n < 4; ++n) acc[m][n] = (f32x4){0.f, 0.f, 0.f, 0.f};

    const unsigned short* Asrc[3] = {A0, A1, A2};
    const unsigned short* Bsrc[3] = {B0, B1, B2};
    const int q    = wid * 2;
    const int srow = lane >> 2;
    const int scol = (lane & 3) * 8;
    const int fr = lane & 15;
    const int fk = (lane >> 4) * 8;

    for (int k0 = 0; k0 < D_; k0 += 32) {
        __syncthreads();
        #pragma unroll
        for (int s = 0; s < 6; ++s) {
            const unsigned short* src = (s < 3) ? Asrc[s] : Bsrc[s - 3];
            const int r0 = (s < 3) ? arow0 : brow0;
            unsigned short* ldsb = smem + s * 4096 + q * 512;
            #pragma unroll
            for (int c = 0; c < 2; ++c) {
                const unsigned short* gp =
                    src + ((size_t)(r0 + (q + c) * 16 + srow) << 8) + k0 + scol;
                gload16(gp, ldsb + c * 512);
            }
        }
        __syncthreads();
        bf16x8 af[3][4];
        #pragma unroll
        for (int l = 0; l < 3; ++l)
            #pragma unroll
            for (int m = 0; m < 4; ++m)
                af[l][m] = *(const bf16x8*)(smem + l * 4096 +
                                            (wr * 64 + m * 16 + fr) * 32 + fk);
        #pragma unroll
        for (int bl = 0; bl < 3; ++bl) {
            bf16x8 bfr[4];
            #pragma unroll
            for (int n = 0; n < 4; ++n)
                bfr[n] = *(const bf16x8*)(smem + (3 + bl) * 4096 +
                                          (wc * 64 + n * 16 + fr) * 32 + fk);
            #pragma unroll
            for (int al = 0; al < 3; ++al) {
                if (al + bl > 2) continue;
                #pragma unroll
                for (int m = 0; m < 4; ++m)
                    #pragma unroll
                    for (int n = 0; n < 4; ++n)
                        acc[m][n] = __builtin_amdgcn_mfma_f32_16x16x32_bf16(
                            af[al][m], bfr[n], acc[m][n], 0, 0, 0);
            }
        }
    }
    const int crow = (lane >> 4) * 4;
    const int ccol = lane & 15;
    #pragma unroll
    for (int m = 0; m < 4; ++m) {
        const int gr = arow0 + wr * 64 + m * 16 + crow;
        #pragma unroll
        for (int n = 0; n < 4; ++n) {
            const int gc = brow0 + wc * 64 + n * 16 + ccol;
            f32x4 v = acc[m][n];
            float bv = BIAS ? bias[gc] : 0.0f;
            #pragma unroll
            for (int r = 0; r < 4; ++r)
                Cout[(size_t)(gr + r) * ldc + gc] = v[r] + bv;
        }
    }
}

__global__ __launch_bounds__(256) void zmm6_kernel(const unsigned short* __restrict__ SP,
                                                   const unsigned short* __restrict__ W1T,
                                                   const float* __restrict__ b1,
                                                   float* __restrict__ Z) {
    __shared__ unsigned short smem[6 * 4096];
    int bv = blockIdx.z;
    mm6_body<true>(SP + (size_t)(bv * 3 + 0) * PLANE,
                   SP + (size_t)(bv * 3 + 1) * PLANE,
                   SP + (size_t)(bv * 3 + 2) * PLANE,
                   W1T, W1T + WPLANE, W1T + 2 * WPLANE,
                   blockIdx.x, blockIdx.y,
                   Z + (size_t)bv * N_ * H_, b1, H_, smem);
}

// ---------------------------------------------------------------------------
__global__ __launch_bounds__(512) void tcode_kernel(const float* __restrict__ T,
                                                    const float* __restrict__ Wt,
                                                    float* __restrict__ tcode) {
    int dp = blockIdx.x;
    int i = dp / 3, rem = dp % 3;
    int j = rem + (rem >= i ? 1 : 0);
    int h = threadIdx.x;
    float acc = 0.0f;
    #pragma unroll
    for (int k = 0; k < 16; k++) acc = fmaf(T[i * 16 + k], Wt[k * H_ + h], acc);
    #pragma unroll
    for (int k = 0; k < 16; k++) acc = fmaf(T[j * 16 + k], Wt[(16 + k) * H_ + h], acc);
    tcode[dp * H_ + h] = acc;
}

// ---------------------------------------------------------------------------
__global__ __launch_bounds__(256) void loss_kernel(const float* __restrict__ Z,
                                                   const float* __restrict__ tcode,
                                                   const float* __restrict__ soft,
                                                   const float* __restrict__ W2,
                                                   const float* __restrict__ b2,
                                                   float* __restrict__ loss_sum) {
    int dd = blockIdx.y;
    int dp = dd >> 1, b = dd & 1;
    int i = dp / 3;
    const float* tc = tcode + (size_t)dp * H_;
    const float* zbase = Z + (size_t)((b * V_ + i) * N_) * H_;
    const float* softb = soft + (size_t)dd * N_ * C_;
    int tid = threadIdx.x;
    int wid = tid >> 6, lane = tid & 63;
    __shared__ float wsum[4];
    float sse_acc = 0.0f;
    float4 t1 = *(const float4*)(tc + lane * 4);
    float4 t2 = *(const float4*)(tc + 256 + lane * 4);
    for (int rr = wid; rr < 64; rr += 4) {
        int n = blockIdx.x * 64 + rr;
        const float* zp = zbase + (size_t)n * H_;
        float4 z1 = *(const float4*)(zp + lane * 4);
        float4 z2 = *(const float4*)(zp + 256 + lane * 4);
        float pre[8] = {z1.x + t1.x, z1.y + t1.y, z1.z + t1.z, z1.w + t1.w,
                        z2.x + t2.x, z2.y + t2.y, z2.z + t2.z, z2.w + t2.w};
        float c0 = 0.f, c1 = 0.f, c2 = 0.f;
        int h1 = lane * 4, h2 = 256 + lane * 4;
        #pragma unroll
        for (int q = 0; q < 8; q++) {
            float rv = fmaxf(pre[q], 0.0f);
            int h = (q < 4) ? (h1 + q) : (h2 + q - 4);
            c0 = fmaf(rv, W2[h * 3 + 0], c0);
            c1 = fmaf(rv, W2[h * 3 + 1], c1);
            c2 = fmaf(rv, W2[h * 3 + 2], c2);
        }
        #pragma unroll
        for (int off = 32; off >= 1; off >>= 1) {
            c0 += __shfl_xor(c0, off, 64);
            c1 += __shfl_xor(c1, off, 64);
            c2 += __shfl_xor(c2, off, 64);
        }
        if (lane == 0) {
            float e0 = c0 + b2[0] - softb[(size_t)n * C_ + 0];
            float e1 = c1 + b2[1] - softb[(size_t)n * C_ + 1];
            float e2 = c2 + b2[2] - softb[(size_t)n * C_ + 2];
            sse_acc += e0 * e0 + e1 * e1 + e2 * e2;
        }
    }
    if (lane == 0) wsum[wid] = sse_acc;
    __syncthreads();
    if (tid == 0) {
        atomicAdd(&loss_sum[dd], wsum[0] + wsum[1] + wsum[2] + wsum[3]);
    }
}

// ---------------------------------------------------------------------------
__global__ __launch_bounds__(64) void final_kernel(const float* __restrict__ loss_sum,
                                                   const int* __restrict__ hm,
                                                   float* __restrict__ out) {
    if (threadIdx.x != 0 || blockIdx.x != 0) return;
    float lt = 0.0f, cnt = 0.0f;
    for (int dp = 0; dp < 12; dp++) {
        int i = dp / 3, rem = dp % 3;
        int j = rem + (rem >= i ? 1 : 0);
        int a = i < j ? i : j, c = i < j ? j : i;
        int p = a * 3 - (a * (a - 1)) / 2 + (c - a - 1);
        for (int b = 0; b < 2; b++) {
            if (hm[p * 2 + b]) {
                lt += loss_sum[dp * 2 + b] * (1.0f / ((float)N_ * (float)C_));
                cnt += 1.0f;
            }
        }
    }
    out[0] = (cnt > 0.0f) ? (lt / cnt) : 0.0f;
}

// ---------------------------------------------------------------------------
extern "C" void kernel_launch(void* const* d_in, const int* in_sizes, int n_in,
                              void* d_out, int out_size, void* d_ws, size_t ws_size,
                              hipStream_t stream) {
    const float* desc = (const float*)d_in[0];
    const float* sf   = (const float*)d_in[1];
    const float* T    = (const float*)d_in[2];
    const float* W1   = (const float*)d_in[3];
    const float* b1   = (const float*)d_in[4];
    const float* Wt   = (const float*)d_in[5];
    const float* W2   = (const float*)d_in[6];
    const float* b2   = (const float*)d_in[7];
    float* out = (float*)d_out;

    // workspace layout
    const size_t NM = (size_t)N_ * N_;
    unsigned short* SP  = (unsigned short*)d_ws;          // 24*PLANE (50.3MB)
    unsigned short* W1T = SP + (size_t)24 * PLANE;        // 3*WPLANE
    float* w     = (float*)(W1T + (size_t)3 * WPLANE);
    float* Z     = w;                                     // NM (67MB)
    float* PT    = w + NM;                                // 12 * 48 * N_ * 8 (75.5MB)
    float* invn  = PT + (size_t)12 * 48 * N_ * 8;         // 32768
    float* tcode = invn + (size_t)B_ * V_ * N_;           // 6144
    float* soft  = tcode + 12 * H_;                       // 294912
    int*   idxbuf = (int*)(soft + (size_t)12 * B_ * N_ * C_); // 12*2*N
    float* loss_sum = (float*)(idxbuf + (size_t)12 * 2 * N_); // 24
    int*   hm    = (int*)(loss_sum + 24);                 // 12

    zero_accum_kernel<<<1, 64, 0, stream>>>(loss_sum, hm);
    split_kernel<<<8192, 256, 0, stream>>>(desc, SP);
    w1split_kernel<<<512, 256, 0, stream>>>(W1, W1T);
    norms_kernel<<<(B_ * V_ * N_) / 4, 256, 0, stream>>>(desc, invn);
    tcode_kernel<<<12, 512, 0, stream>>>(T, Wt, tcode);

    const int pairs[6][2] = {{0, 1}, {0, 2}, {0, 3}, {1, 2}, {1, 3}, {2, 3}};
    for (int p = 0; p < 6; p++) {
        int i = pairs[p][0], j = pairs[p][1];
        for (int b = 0; b < 2; b++) {
            int u = p * 2 + b;
            float* RPu = PT + (size_t)u * 48 * N_ * 8;
            float* CPu = RPu + (size_t)16 * N_ * 8;
            fgram_kernel<<<512, 256, 0, stream>>>(SP, sf, invn, b, i, j, RPu, CPu);
        }
    }

    zmm6_kernel<<<dim3(32, 4, 8), 256, 0, stream>>>(SP, W1T, b1, Z);
    comb_kernel<<<dim3(32, 12), 256, 0, stream>>>(PT, soft, idxbuf);
    mutualB_kernel<<<dim3(16, 12), 256, 0, stream>>>(idxbuf, hm);
    loss_kernel<<<dim3(64, 24), 256, 0, stream>>>(Z, tcode, soft, W2, b2, loss_sum);
    final_kernel<<<1, 64, 0, stream>>>(loss_sum, hm, out);
}

// Round 8
// 1544.602 us; speedup vs baseline: 1.2046x; 1.0395x over previous
//
#include <hip/hip_runtime.h>
#include <cstdint>
#include <cstddef>

// Problem constants
#define N_ 4096
#define B_ 2
#define V_ 4
#define D_ 256
#define C_ 3
#define H_ 512

#define PLANE 1048576   // N_*D_ elements per split plane
#define WPLANE 131072   // H_*D_ elements per W1T split plane
#define NEG_INF (-__builtin_inff())
#define TSTRIDE 130     // f32 tile row stride (words)

typedef __attribute__((ext_vector_type(8))) short bf16x8;   // 8 bf16 in 4 VGPRs
typedef __attribute__((ext_vector_type(4))) float f32x4;

// ---------------------------------------------------------------------------
__device__ __forceinline__ void gload16(const void* g, void* l) {
    __builtin_amdgcn_global_load_lds(
        (const __attribute__((address_space(1))) void*)g,
        (__attribute__((address_space(3))) void*)l,
        16, 0, 0);
}

// RNE float->bf16
__device__ __forceinline__ unsigned short f2bf(float x) {
    unsigned u = __builtin_bit_cast(unsigned, x);
    u += 0x7FFFu + ((u >> 16) & 1u);
    return (unsigned short)(u >> 16);
}
__device__ __forceinline__ float bf2f(unsigned short h) {
    unsigned u = ((unsigned)h) << 16;
    return __builtin_bit_cast(float, u);
}
__device__ __forceinline__ void split3(float x, unsigned short& h, unsigned short& m,
                                       unsigned short& l) {
    h = f2bf(x);
    float r = x - bf2f(h);
    m = f2bf(r);
    l = f2bf(r - bf2f(m));
}

// ---------------------------------------------------------------------------
__global__ __launch_bounds__(64) void zero_accum_kernel(float* loss_sum, int* hm) {
    int t = threadIdx.x;
    if (t < 24) loss_sum[t] = 0.0f;
    if (t < 12) hm[t] = 0;
}

// ---------------------------------------------------------------------------
// Split desc fp32 -> 3 bf16 planes per (b,v):  SP[(bv*3+l)][n][d]
__global__ __launch_bounds__(256) void split_kernel(const float* __restrict__ desc,
                                                    unsigned short* __restrict__ SP) {
    int t = blockIdx.x * 256 + threadIdx.x;
    int d4 = t & 63;
    int v  = (t >> 6) & 3;
    int n  = (t >> 8) & 4095;
    int b  = t >> 20;
    const float4 x = *(const float4*)(desc + (((size_t)(b * N_ + n) * V_ + v) << 8) + d4 * 4);
    ushort4 hv, mv, lv;
    split3(x.x, hv.x, mv.x, lv.x);
    split3(x.y, hv.y, mv.y, lv.y);
    split3(x.z, hv.z, mv.z, lv.z);
    split3(x.w, hv.w, mv.w, lv.w);
    size_t base = (size_t)((b * V_ + v) * 3) * PLANE + n * D_ + d4 * 4;
    *(ushort4*)(SP + base)              = hv;
    *(ushort4*)(SP + base + PLANE)      = mv;
    *(ushort4*)(SP + base + 2 * PLANE)  = lv;
}

// W1 [D][H] -> transposed split planes W1T[l][h][k]
__global__ __launch_bounds__(256) void w1split_kernel(const float* __restrict__ W1,
                                                      unsigned short* __restrict__ W1T) {
    int t = blockIdx.x * 256 + threadIdx.x;
    int h = t & 511;
    int k = t >> 9;
    float x = W1[(size_t)k * H_ + h];
    unsigned short hv, mv, lv;
    split3(x, hv, mv, lv);
    size_t o = (size_t)h * D_ + k;
    W1T[o] = hv; W1T[o + WPLANE] = mv; W1T[o + 2 * WPLANE] = lv;
}

// ---------------------------------------------------------------------------
__global__ __launch_bounds__(256) void norms_kernel(const float* __restrict__ desc,
                                                    float* __restrict__ invn) {
    int gw   = (blockIdx.x * 256 + threadIdx.x) >> 6;
    int lane = threadIdx.x & 63;
    int bv = gw >> 12;
    int n  = gw & (N_ - 1);
    int b  = bv >> 2, v = bv & 3;
    const float* p = desc + ((size_t)(b * N_ + n) * V_ + v) * D_;
    float4 x = *(const float4*)(p + lane * 4);
    float s = x.x * x.x + x.y * x.y + x.z * x.z + x.w * x.w;
    #pragma unroll
    for (int off = 32; off >= 1; off >>= 1) s += __shfl_xor(s, off, 64);
    if (lane == 0) invn[gw] = 1.0f / fmaxf(sqrtf(s), 1e-12f);
}

// ---------------------------------------------------------------------------
// FUSED gram + row/col softmax/argmax reductions (never materializes S).
// Epilogue v3: one tile-wide max -> single-pass scans, plain-add merges,
// everything unioned into the 48KB staging LDS (44.5KB total -> 3 blocks/CU).
// Partials: RP[(chunk*2+t)][n][8] rows, CP[strip][m][8] cols (M field = mxt).
__global__ __launch_bounds__(256) void fgram_kernel(
    const unsigned short* __restrict__ SP,
    const float* __restrict__ sf,
    const float* __restrict__ invn,
    int b, int i, int j,
    float* __restrict__ RP,
    float* __restrict__ CP) {
    __shared__ __align__(16) unsigned char smraw[49152];
    __shared__ float wmax[4];
    unsigned short* stage = (unsigned short*)smraw;            // 48KB (K-loop)
    float* tile  = (float*)smraw;                              // [64][130] = 33280B
    float* CSb   = (float*)(smraw + 33280);                    // [128][9]  = 4608B
    float4* sfj4 = (float4*)(smraw + 37888);                   // [256]     = 4096B
    float4* sfi4 = (float4*)(smraw + 41984);                   // [128]     = 2048B  (ends 44032)

    const int tid = threadIdx.x;
    const int wid = tid >> 6, lane = tid & 63;
    const int wr = wid >> 1, wc = wid & 1;
    const int g = lane >> 4, ccol = lane & 15;

    const int bid = blockIdx.x;                    // 0..511 (512%8==0 -> bijective)
    const int swz = (bid & 7) * 64 + (bid >> 3);
    const int strip = swz >> 4, chunk = swz & 15;
    const int n0 = strip * 128, m0 = chunk * 256;

    const int gA = b * V_ + i, gB = b * V_ + j;

    const int q    = wid * 2;
    const int srow = lane >> 2;
    const int scol = (lane & 3) * 8;
    const int fr   = lane & 15;
    const int fk   = g * 8;

    for (int t = 0; t < 2; ++t) {
        const int brow0 = m0 + t * 128;

        f32x4 acc[4][4];
        #pragma unroll
        for (int m = 0; m < 4; ++m)
            #pragma unroll
            for (int n = 0; n < 4; ++n) acc[m][n] = (f32x4){0.f, 0.f, 0.f, 0.f};

        for (int k0 = 0; k0 < D_; k0 += 32) {
            __syncthreads();
            #pragma unroll
            for (int pl = 0; pl < 6; ++pl) {
                const unsigned short* src = (pl < 3)
                    ? (SP + (size_t)(gA * 3 + pl) * PLANE)
                    : (SP + (size_t)(gB * 3 + pl - 3) * PLANE);
                const int r0 = (pl < 3) ? n0 : brow0;
                unsigned short* ldsb = stage + pl * 4096 + q * 512;
                #pragma unroll
                for (int c = 0; c < 2; ++c) {
                    const unsigned short* gp =
                        src + ((size_t)(r0 + (q + c) * 16 + srow) << 8) + k0 + scol;
                    gload16(gp, ldsb + c * 512);
                }
            }
            __syncthreads();

            bf16x8 af[3][4];
            #pragma unroll
            for (int l = 0; l < 3; ++l)
                #pragma unroll
                for (int m = 0; m < 4; ++m)
                    af[l][m] = *(const bf16x8*)(stage + l * 4096 +
                                                (wr * 64 + m * 16 + fr) * 32 + fk);
            #pragma unroll
            for (int bl = 0; bl < 3; ++bl) {
                bf16x8 bfr[4];
                #pragma unroll
                for (int n = 0; n < 4; ++n)
                    bfr[n] = *(const bf16x8*)(stage + (3 + bl) * 4096 +
                                              (wc * 64 + n * 16 + fr) * 32 + fk);
                #pragma unroll
                for (int al = 0; al < 3; ++al) {
                    if (al + bl > 2) continue;
                    #pragma unroll
                    for (int m = 0; m < 4; ++m)
                        #pragma unroll
                        for (int n = 0; n < 4; ++n)
                            acc[m][n] = __builtin_amdgcn_mfma_f32_16x16x32_bf16(
                                af[al][m], bfr[n], acc[m][n], 0, 0, 0);
                }
            }
        }

        // ---- tile-wide max ----
        float tmax = NEG_INF;
        #pragma unroll
        for (int m = 0; m < 4; ++m)
            #pragma unroll
            for (int n = 0; n < 4; ++n)
                #pragma unroll
                for (int r = 0; r < 4; ++r)
                    tmax = fmaxf(tmax, acc[m][n][r]);
        #pragma unroll
        for (int off = 1; off <= 32; off <<= 1)
            tmax = fmaxf(tmax, __shfl_xor(tmax, off, 64));
        if (lane == 0) wmax[wid] = tmax;
        __syncthreads();   // wmax visible; all MFMA/staging reads complete
        const float mxt = fmaxf(fmaxf(wmax[0], wmax[1]), fmaxf(wmax[2], wmax[3]));

        // load sf/invn tables into the (now free) staging-tail region
        {
            int m = m0 + t * 128 + (tid & 127);   // tile's 128 chunk cols
            if (tid < 128) {
                const float* p = sf + (((size_t)(b * N_ + m)) * V_ + j) * C_;
                sfj4[tid] = make_float4(p[0], p[1], p[2], invn[(size_t)gB * N_ + m]);
            } else {
                int n = n0 + (tid & 127);
                const float* p = sf + (((size_t)(b * N_ + n)) * V_ + i) * C_;
                sfi4[tid & 127] = make_float4(p[0], p[1], p[2], invn[(size_t)gA * N_ + n]);
            }
        }

        for (int half = 0; half < 2; ++half) {
            if (wr == half) {
                #pragma unroll
                for (int m = 0; m < 4; ++m)
                    #pragma unroll
                    for (int nf = 0; nf < 4; ++nf) {
                        int c = wc * 64 + nf * 16 + ccol;
                        int rb = m * 16 + g * 4;
                        #pragma unroll
                        for (int r = 0; r < 4; ++r)
                            tile[(rb + r) * TSTRIDE + c] = acc[m][nf][r];
                    }
            }
            __syncthreads();  // tile + sf tables visible

            // ---- row scan: 64 rows x 4 quarters, single pass ----
            {
                const int row = tid >> 2, qq = tid & 3;
                const float* rp = tile + row * TSTRIDE;
                float sum = 0.f, w0 = 0.f, w1 = 0.f, w2 = 0.f;
                float bv = NEG_INF, bif = (float)N_;
                for (int ii = 0; ii < 32; ++ii) {
                    int c = (ii << 2) + qq;
                    float s = rp[c];
                    float4 sp = sfj4[c];
                    float e = __expf(s - mxt);
                    sum += e;
                    w0 = fmaf(e, sp.x, w0); w1 = fmaf(e, sp.y, w1); w2 = fmaf(e, sp.z, w2);
                    float vv = s * sp.w;
                    float gi = (float)(m0 + t * 128 + c);
                    if (vv > bv || (vv == bv && gi < bif)) { bv = vv; bif = gi; }
                }
                #pragma unroll
                for (int off = 1; off <= 2; off <<= 1) {
                    sum += __shfl_xor(sum, off, 64);
                    w0  += __shfl_xor(w0, off, 64);
                    w1  += __shfl_xor(w1, off, 64);
                    w2  += __shfl_xor(w2, off, 64);
                    float ob = __shfl_xor(bv, off, 64);
                    float oi = __shfl_xor(bif, off, 64);
                    if (ob > bv || (ob == bv && oi < bif)) { bv = ob; bif = oi; }
                }
                if (qq == 0) {
                    float* o = RP + ((size_t)(chunk * 2 + t) * N_ + n0 + half * 64 + row) * 8;
                    *(float4*)o       = make_float4(mxt, sum, w0, w1);
                    *(float4*)(o + 4) = make_float4(w2, bv, bif, 0.f);
                }
            }

            // ---- col scan: 128 cols x 2 row-halves, single pass ----
            {
                const int c = tid >> 1, h = tid & 1;
                const float* cp = tile + (h * 32) * TSTRIDE + c;
                const int rb0 = half * 64 + h * 32;
                float sum = 0.f, w0 = 0.f, w1 = 0.f, w2 = 0.f;
                float bv = NEG_INF, bif = (float)N_;
                for (int ii = 0; ii < 32; ++ii) {
                    float s = cp[ii * TSTRIDE];
                    float4 sp = sfi4[rb0 + ii];
                    float e = __expf(s - mxt);
                    sum += e;
                    w0 = fmaf(e, sp.x, w0); w1 = fmaf(e, sp.y, w1); w2 = fmaf(e, sp.z, w2);
                    float vv = s * sp.w;
                    float gi = (float)(n0 + rb0 + ii);
                    if (vv > bv || (vv == bv && gi < bif)) { bv = vv; bif = gi; }
                }
                {
                    sum += __shfl_xor(sum, 1, 64);
                    w0  += __shfl_xor(w0, 1, 64);
                    w1  += __shfl_xor(w1, 1, 64);
                    w2  += __shfl_xor(w2, 1, 64);
                    float ob = __shfl_xor(bv, 1, 64);
                    float oi = __shfl_xor(bif, 1, 64);
                    if (ob > bv || (ob == bv && oi < bif)) { bv = ob; bif = oi; }
                }
                if (h == 0) {
                    float* cs = CSb + c * 9;
                    if (half == 0) {
                        cs[0] = sum; cs[1] = w0; cs[2] = w1; cs[3] = w2;
                        cs[4] = bv;  cs[5] = bif;
                    } else {
                        cs[0] += sum; cs[1] += w0; cs[2] += w1; cs[3] += w2;
                        if (bv > cs[4] || (bv == cs[4] && bif < cs[5])) { cs[4] = bv; cs[5] = bif; }
                    }
                }
            }
            __syncthreads();  // scans done before tile overwrite / flush
        }

        // flush col partials for this tile
        if (tid < 128) {
            const float* cs = CSb + tid * 9;
            float* o = CP + ((size_t)strip * N_ + m0 + t * 128 + tid) * 8;
            *(float4*)o       = make_float4(mxt, cs[0], cs[1], cs[2]);
            *(float4*)(o + 4) = make_float4(cs[3], cs[4], cs[5], 0.f);
        }
        // K-loop-top barrier (next t) orders flush vs restaging
    }
}

// ---------------------------------------------------------------------------
// Combine partials (K=32 both directions) -> soft + argmax indices.
// blockIdx.y = unit u (p*2+b); blockIdx.x: 0..15 rows, 16..31 cols.
__global__ __launch_bounds__(256) void comb_kernel(const float* __restrict__ PT,
                                                   float* __restrict__ soft,
                                                   int* __restrict__ idxbuf) {
    const int pi[6] = {0, 0, 0, 1, 1, 2}, pj[6] = {1, 2, 3, 2, 3, 3};
    int u = blockIdx.y, p = u >> 1, b = u & 1;
    int i = pi[p], j = pj[p];
    int x = blockIdx.x;
    int idx = (x & 15) * 256 + threadIdx.x;
    const size_t unit = (size_t)u * 64 * N_ * 8;
    const float* base;
    int dd, which;
    if (x < 16) { base = PT + unit + (size_t)idx * 8;                       dd = (i * 3 + (j - 1)) * 2 + b; which = 0; }
    else        { base = PT + unit + (size_t)32 * N_ * 8 + (size_t)idx * 8; dd = (j * 3 + i) * 2 + b;       which = 1; }

    float4 a = *(const float4*)base;
    float4 b4 = *(const float4*)(base + 4);
    float M = a.x, S = a.y, w0 = a.z, w1 = a.w, w2 = b4.x, av = b4.y, ai = b4.z;
    for (int k = 1; k < 32; ++k) {
        const float* qp = base + (size_t)k * N_ * 8;
        float4 c = *(const float4*)qp;
        float4 d = *(const float4*)(qp + 4);
        if (c.x > M) {
            float e = __expf(M - c.x);
            M = c.x;
            S  = fmaf(S,  e, c.y);
            w0 = fmaf(w0, e, c.z);
            w1 = fmaf(w1, e, c.w);
            w2 = fmaf(w2, e, d.x);
        } else {
            float e = __expf(c.x - M);
            S  = fmaf(c.y, e, S);
            w0 = fmaf(c.z, e, w0);
            w1 = fmaf(c.w, e, w1);
            w2 = fmaf(d.x, e, w2);
        }
        if (d.y > av || (d.y == av && d.z < ai)) { av = d.y; ai = d.z; }
    }
    float inv = 1.0f / S;
    float* so = soft + ((size_t)dd * N_ + idx) * 3;
    so[0] = w0 * inv; so[1] = w1 * inv; so[2] = w2 * inv;
    idxbuf[((size_t)u * 2 + which) * N_ + idx] = (int)ai;
}

// ---------------------------------------------------------------------------
__global__ __launch_bounds__(256) void mutualB_kernel(const int* __restrict__ idxbuf,
                                                      int* __restrict__ hm) {
    int u = blockIdx.y;
    int n = blockIdx.x * 256 + threadIdx.x;
    int a = idxbuf[((size_t)u * 2 + 0) * N_ + n];
    int ok = (idxbuf[((size_t)u * 2 + 1) * N_ + a] == n) ? 1 : 0;
    unsigned long long m = __ballot(ok);
    if ((threadIdx.x & 63) == 0 && m != 0ull) atomicOr(&hm[u], 1);
}

// ---------------------------------------------------------------------------
// Z GEMM (bf16x6 emulated fp32), m97-style body
template<bool BIAS>
__device__ __forceinline__ void mm6_body(
    const unsigned short* __restrict__ A0, const unsigned short* __restrict__ A1,
    const unsigned short* __restrict__ A2,
    const unsigned short* __restrict__ B0, const unsigned short* __restrict__ B1,
    const unsigned short* __restrict__ B2,
    int bx, int by,
    float* __restrict__ Cout, const float* __restrict__ bias, int ldc,
    unsigned short* smem) {
    const int tid = threadIdx.x;
    const int wid = tid >> 6, lane = tid & 63;
    const int wr = wid >> 1, wc = wid & 1;
    const int arow0 = bx * 128, brow0 = by * 128;

    f32x4 acc[4][4];
    #pragma unroll
    for (int m = 0; m < 4; ++m)
        #pragma unroll
        for (int n = 0; n < 4; ++n) acc[m][n] = (f32x4){0.f, 0.f, 0.f, 0.f};

    const unsigned short* Asrc[3] = {A0, A1, A2};
    const unsigned short* Bsrc[3] = {B0, B1, B2};
    const int q    = wid * 2;
    const int srow = lane >> 2;
    const int scol = (lane & 3) * 8;
    const int fr = lane & 15;
    const int fk = (lane >> 4) * 8;

    for (int k0 = 0; k0 < D_; k0 += 32) {
        __syncthreads();
        #pragma unroll
        for (int s = 0; s < 6; ++s) {
            const unsigned short* src = (s < 3) ? Asrc[s] : Bsrc[s - 3];
            const int r0 = (s < 3) ? arow0 : brow0;
            unsigned short* ldsb = smem + s * 4096 + q * 512;
            #pragma unroll
            for (int c = 0; c < 2; ++c) {
                const unsigned short* gp =
                    src + ((size_t)(r0 + (q + c) * 16 + srow) << 8) + k0 + scol;
                gload16(gp, ldsb + c * 512);
            }
        }
        __syncthreads();
        bf16x8 af[3][4];
        #pragma unroll
        for (int l = 0; l < 3; ++l)
            #pragma unroll
            for (int m = 0; m < 4; ++m)
                af[l][m] = *(const bf16x8*)(smem + l * 4096 +
                                            (wr * 64 + m * 16 + fr) * 32 + fk);
        #pragma unroll
        for (int bl = 0; bl < 3; ++bl) {
            bf16x8 bfr[4];
            #pragma unroll
            for (int n = 0; n < 4; ++n)
                bfr[n] = *(const bf16x8*)(smem + (3 + bl) * 4096 +
                                          (wc * 64 + n * 16 + fr) * 32 + fk);
            #pragma unroll
            for (int al = 0; al < 3; ++al) {
                if (al + bl > 2) continue;
                #pragma unroll
                for (int m = 0; m < 4; ++m)
                    #pragma unroll
                    for (int n = 0; n < 4; ++n)
                        acc[m][n] = __builtin_amdgcn_mfma_f32_16x16x32_bf16(
                            af[al][m], bfr[n], acc[m][n], 0, 0, 0);
            }
        }
    }
    const int crow = (lane >> 4) * 4;
    const int ccol = lane & 15;
    #pragma unroll
    for (int m = 0; m < 4; ++m) {
        const int gr = arow0 + wr * 64 + m * 16 + crow;
        #pragma unroll
        for (int n = 0; n < 4; ++n) {
            const int gc = brow0 + wc * 64 + n * 16 + ccol;
            f32x4 v = acc[m][n];
            float bv = BIAS ? bias[gc] : 0.0f;
            #pragma unroll
            for (int r = 0; r < 4; ++r)
                Cout[(size_t)(gr + r) * ldc + gc] = v[r] + bv;
        }
    }
}

__global__ __launch_bounds__(256) void zmm6_kernel(const unsigned short* __restrict__ SP,
                                                   const unsigned short* __restrict__ W1T,
                                                   const float* __restrict__ b1,
                                                   float* __restrict__ Z) {
    __shared__ unsigned short smem[6 * 4096];
    int bv = blockIdx.z;
    mm6_body<true>(SP + (size_t)(bv * 3 + 0) * PLANE,
                   SP + (size_t)(bv * 3 + 1) * PLANE,
                   SP + (size_t)(bv * 3 + 2) * PLANE,
                   W1T, W1T + WPLANE, W1T + 2 * WPLANE,
                   blockIdx.x, blockIdx.y,
                   Z + (size_t)bv * N_ * H_, b1, H_, smem);
}

// ---------------------------------------------------------------------------
__global__ __launch_bounds__(512) void tcode_kernel(const float* __restrict__ T,
                                                    const float* __restrict__ Wt,
                                                    float* __restrict__ tcode) {
    int dp = blockIdx.x;
    int i = dp / 3, rem = dp % 3;
    int j = rem + (rem >= i ? 1 : 0);
    int h = threadIdx.x;
    float acc = 0.0f;
    #pragma unroll
    for (int k = 0; k < 16; k++) acc = fmaf(T[i * 16 + k], Wt[k * H_ + h], acc);
    #pragma unroll
    for (int k = 0; k < 16; k++) acc = fmaf(T[j * 16 + k], Wt[(16 + k) * H_ + h], acc);
    tcode[dp * H_ + h] = acc;
}

// ---------------------------------------------------------------------------
__global__ __launch_bounds__(256) void loss_kernel(const float* __restrict__ Z,
                                                   const float* __restrict__ tcode,
                                                   const float* __restrict__ soft,
                                                   const float* __restrict__ W2,
                                                   const float* __restrict__ b2,
                                                   float* __restrict__ loss_sum) {
    int dd = blockIdx.y;
    int dp = dd >> 1, b = dd & 1;
    int i = dp / 3;
    const float* tc = tcode + (size_t)dp * H_;
    const float* zbase = Z + (size_t)((b * V_ + i) * N_) * H_;
    const float* softb = soft + (size_t)dd * N_ * C_;
    int tid = threadIdx.x;
    int wid = tid >> 6, lane = tid & 63;
    __shared__ float wsum[4];
    float sse_acc = 0.0f;
    float4 t1 = *(const float4*)(tc + lane * 4);
    float4 t2 = *(const float4*)(tc + 256 + lane * 4);
    for (int rr = wid; rr < 64; rr += 4) {
        int n = blockIdx.x * 64 + rr;
        const float* zp = zbase + (size_t)n * H_;
        float4 z1 = *(const float4*)(zp + lane * 4);
        float4 z2 = *(const float4*)(zp + 256 + lane * 4);
        float pre[8] = {z1.x + t1.x, z1.y + t1.y, z1.z + t1.z, z1.w + t1.w,
                        z2.x + t2.x, z2.y + t2.y, z2.z + t2.z, z2.w + t2.w};
        float c0 = 0.f, c1 = 0.f, c2 = 0.f;
        int h1 = lane * 4, h2 = 256 + lane * 4;
        #pragma unroll
        for (int q = 0; q < 8; q++) {
            float rv = fmaxf(pre[q], 0.0f);
            int h = (q < 4) ? (h1 + q) : (h2 + q - 4);
            c0 = fmaf(rv, W2[h * 3 + 0], c0);
            c1 = fmaf(rv, W2[h * 3 + 1], c1);
            c2 = fmaf(rv, W2[h * 3 + 2], c2);
        }
        #pragma unroll
        for (int off = 32; off >= 1; off >>= 1) {
            c0 += __shfl_xor(c0, off, 64);
            c1 += __shfl_xor(c1, off, 64);
            c2 += __shfl_xor(c2, off, 64);
        }
        if (lane == 0) {
            float e0 = c0 + b2[0] - softb[(size_t)n * C_ + 0];
            float e1 = c1 + b2[1] - softb[(size_t)n * C_ + 1];
            float e2 = c2 + b2[2] - softb[(size_t)n * C_ + 2];
            sse_acc += e0 * e0 + e1 * e1 + e2 * e2;
        }
    }
    if (lane == 0) wsum[wid] = sse_acc;
    __syncthreads();
    if (tid == 0) {
        atomicAdd(&loss_sum[dd], wsum[0] + wsum[1] + wsum[2] + wsum[3]);
    }
}

// ---------------------------------------------------------------------------
__global__ __launch_bounds__(64) void final_kernel(const float* __restrict__ loss_sum,
                                                   const int* __restrict__ hm,
                                                   float* __restrict__ out) {
    if (threadIdx.x != 0 || blockIdx.x != 0) return;
    float lt = 0.0f, cnt = 0.0f;
    for (int dp = 0; dp < 12; dp++) {
        int i = dp / 3, rem = dp % 3;
        int j = rem + (rem >= i ? 1 : 0);
        int a = i < j ? i : j, c = i < j ? j : i;
        int p = a * 3 - (a * (a - 1)) / 2 + (c - a - 1);
        for (int b = 0; b < 2; b++) {
            if (hm[p * 2 + b]) {
                lt += loss_sum[dp * 2 + b] * (1.0f / ((float)N_ * (float)C_));
                cnt += 1.0f;
            }
        }
    }
    out[0] = (cnt > 0.0f) ? (lt / cnt) : 0.0f;
}

// ---------------------------------------------------------------------------
extern "C" void kernel_launch(void* const* d_in, const int* in_sizes, int n_in,
                              void* d_out, int out_size, void* d_ws, size_t ws_size,
                              hipStream_t stream) {
    const float* desc = (const float*)d_in[0];
    const float* sf   = (const float*)d_in[1];
    const float* T    = (const float*)d_in[2];
    const float* W1   = (const float*)d_in[3];
    const float* b1   = (const float*)d_in[4];
    const float* Wt   = (const float*)d_in[5];
    const float* W2   = (const float*)d_in[6];
    const float* b2   = (const float*)d_in[7];
    float* out = (float*)d_out;

    // workspace layout
    const size_t NM = (size_t)N_ * N_;
    unsigned short* SP  = (unsigned short*)d_ws;          // 24*PLANE (50.3MB)
    unsigned short* W1T = SP + (size_t)24 * PLANE;        // 3*WPLANE
    float* w     = (float*)(W1T + (size_t)3 * WPLANE);
    float* Z     = w;                                     // NM (67MB)
    float* PT    = w + NM;                                // 12 * 64 * N_ * 8 (100.7MB)
    float* invn  = PT + (size_t)12 * 64 * N_ * 8;         // 32768
    float* tcode = invn + (size_t)B_ * V_ * N_;           // 6144
    float* soft  = tcode + 12 * H_;                       // 294912
    int*   idxbuf = (int*)(soft + (size_t)12 * B_ * N_ * C_); // 12*2*N
    float* loss_sum = (float*)(idxbuf + (size_t)12 * 2 * N_); // 24
    int*   hm    = (int*)(loss_sum + 24);                 // 12

    zero_accum_kernel<<<1, 64, 0, stream>>>(loss_sum, hm);
    split_kernel<<<8192, 256, 0, stream>>>(desc, SP);
    w1split_kernel<<<512, 256, 0, stream>>>(W1, W1T);
    norms_kernel<<<(B_ * V_ * N_) / 4, 256, 0, stream>>>(desc, invn);
    tcode_kernel<<<12, 512, 0, stream>>>(T, Wt, tcode);

    const int pairs[6][2] = {{0, 1}, {0, 2}, {0, 3}, {1, 2}, {1, 3}, {2, 3}};
    for (int p = 0; p < 6; p++) {
        int i = pairs[p][0], j = pairs[p][1];
        for (int b = 0; b < 2; b++) {
            int u = p * 2 + b;
            float* RPu = PT + (size_t)u * 64 * N_ * 8;
            float* CPu = RPu + (size_t)32 * N_ * 8;
            fgram_kernel<<<512, 256, 0, stream>>>(SP, sf, invn, b, i, j, RPu, CPu);
        }
    }

    zmm6_kernel<<<dim3(32, 4, 8), 256, 0, stream>>>(SP, W1T, b1, Z);
    comb_kernel<<<dim3(32, 12), 256, 0, stream>>>(PT, soft, idxbuf);
    mutualB_kernel<<<dim3(16, 12), 256, 0, stream>>>(idxbuf, hm);
    loss_kernel<<<dim3(64, 24), 256, 0, stream>>>(Z, tcode, soft, W2, b2, loss_sum);
    final_kernel<<<1, 64, 0, stream>>>(loss_sum, hm, out);
}